// Round 1
// baseline (1425.071 us; speedup 1.0000x reference)
//
#include <hip/hip_runtime.h>
#include <hip/hip_bf16.h>

typedef __attribute__((ext_vector_type(8))) short short8;
typedef __attribute__((ext_vector_type(4))) float f32x4;

__device__ __forceinline__ unsigned short f2bf(float f){
  __hip_bfloat16 h = __float2bfloat16(f);
  return *reinterpret_cast<unsigned short*>(&h);
}

__device__ __forceinline__ float gelu_t(float x){
  // jax.nn.gelu default (approximate=True): 0.5x(1+tanh(sqrt(2/pi)(x+0.044715x^3)))
  float u = 0.7978845608028654f * (x + 0.044715f * x * x * x);
  float e = __expf(2.0f * u);
  float t = 1.0f - 2.0f / (e + 1.0f);
  return 0.5f * x * (1.0f + t);
}

// ---------------- histogram ----------------
__global__ void k_hist(const int* __restrict__ sp, int* __restrict__ cnt, int N){
  int i = blockIdx.x * blockDim.x + threadIdx.x;
  if (i < N) atomicAdd(&cnt[sp[i]], 1);
}

// ---------------- exclusive scan (single block) ----------------
__global__ void k_scan(const int* __restrict__ cnt, int* __restrict__ starts, int S){
  __shared__ int part[256];
  int tid = threadIdx.x;
  int chunk = (S + 255) / 256;
  int lo = tid * chunk;
  int hi = min(lo + chunk, S);
  int sum = 0;
  for (int i = lo; i < hi; i++) sum += cnt[i];
  part[tid] = sum;
  __syncthreads();
  if (tid == 0){
    int run = 0;
    for (int i = 0; i < 256; i++){ int v = part[i]; part[i] = run; run += v; }
  }
  __syncthreads();
  int run = part[tid];
  for (int i = lo; i < hi; i++){ starts[i] = run; run += cnt[i]; }
}

// ---------------- scatter (arbitrary order within segment) ----------------
__global__ void k_scatter(const int* __restrict__ sp, const int* __restrict__ starts,
                          int* __restrict__ fill, int* __restrict__ perm, int N){
  int i = blockIdx.x * blockDim.x + threadIdx.x;
  if (i < N){
    int s = sp[i];
    int pos = atomicAdd(&fill[s], 1);
    perm[starts[s] + pos] = i;
  }
}

// ---------------- stable rank fix: one wave per superpoint ----------------
#define MAXC 512
__global__ void k_rank(const int* __restrict__ perm, const int* __restrict__ starts,
                       const int* __restrict__ cnt, int* __restrict__ perm2, int S){
  __shared__ int buf[4][MAXC];
  int wv = threadIdx.x >> 6;
  int lane = threadIdx.x & 63;
  int s = blockIdx.x * 4 + wv;
  int st = 0, c = 0;
  if (s < S){ st = starts[s]; c = cnt[s]; }
  if (c <= MAXC){
    for (int j = lane; j < c; j += 64) buf[wv][j] = perm[st + j];
  }
  __syncthreads();
  if (c <= MAXC){
    for (int j = lane; j < c; j += 64){
      int v = buf[wv][j];
      int r = 0;
      for (int m = 0; m < c; m++) r += (buf[wv][m] < v) ? 1 : 0;
      perm2[st + r] = v;   // stable order = ascending original index
    }
  } else {
    for (int j = lane; j < c; j += 64) perm2[st + j] = perm[st + j];
  }
}

// ---------------- segment mean: one block (D threads) per superpoint ----------------
__global__ void k_pool(const float* __restrict__ raw, const int* __restrict__ perm,
                       const int* __restrict__ starts, const int* __restrict__ cnt,
                       float* __restrict__ xsp, int D){
  int s = blockIdx.x;
  int d = threadIdx.x;
  int st = starts[s], c = cnt[s];
  float a0 = 0.f, a1 = 0.f, a2 = 0.f, a3 = 0.f;
  int m = 0;
  for (; m + 4 <= c; m += 4){
    int r0 = perm[st + m], r1 = perm[st + m + 1], r2 = perm[st + m + 2], r3 = perm[st + m + 3];
    a0 += raw[(size_t)r0 * D + d];
    a1 += raw[(size_t)r1 * D + d];
    a2 += raw[(size_t)r2 * D + d];
    a3 += raw[(size_t)r3 * D + d];
  }
  for (; m < c; m++) a0 += raw[(size_t)perm[st + m] * D + d];
  float sum = (a0 + a1) + (a2 + a3);
  xsp[(size_t)s * D + d] = sum / (float)max(c, 1);
}

// ---------------- transpose-cast fp32 [A][B] -> bf16 [B][A] ----------------
__global__ void k_castT(const float* __restrict__ in, unsigned short* __restrict__ out,
                        int A, int B){
  int i = blockIdx.x * blockDim.x + threadIdx.x;
  if (i >= A * B) return;
  int b = i / A, a = i - b * A;
  out[(size_t)b * A + a] = f2bf(in[(size_t)a * B + b]);
}

// ---------------- build seq (bf16 tokens): one block (64 thr) per token ----------------
__global__ void k_seq(const float* __restrict__ raw, const float* __restrict__ xsp,
                      const int* __restrict__ perm2, const int* __restrict__ starts,
                      const int* __restrict__ cnt, const int* __restrict__ rnd,
                      unsigned short* __restrict__ seq, int S, int K, int N, int D){
  int t = blockIdx.x;
  int lane = threadIdx.x;      // 64 threads, float4 each => 256 floats
  int kp1 = K + 1;
  int s = t / kp1;
  int j = t - s * kp1;
  const float* src;
  if (j < K){
    int c = cnt[s];
    int ml = max(c, 1);
    int gi = starts[s] + (rnd[s * K + j] % ml);
    gi = min(gi, N - 1);
    src = raw + (size_t)perm2[gi] * D;
  } else {
    src = xsp + (size_t)s * D;
  }
  float4 v = reinterpret_cast<const float4*>(src)[lane];
  ushort4 o;
  o.x = f2bf(v.x); o.y = f2bf(v.y); o.z = f2bf(v.z); o.w = f2bf(v.w);
  reinterpret_cast<ushort4*>(seq + (size_t)t * D)[lane] = o;
}

// ---------------- fused MLP: seq(64 tok)@W1 -> GELU -> @W2, bf16 MFMA ----------------
// D=256, HID=1024 hardcoded. LDS (shorts): seq[64][264], w1[64][264], w2[256][72], h[64][72]
#define SEQ_STRIDE 264
#define W2_STRIDE  72
#define H_STRIDE   72
__global__ __launch_bounds__(256)
void k_mlp(const unsigned short* __restrict__ seq, const unsigned short* __restrict__ w1t,
           const unsigned short* __restrict__ w2t, const float* __restrict__ bias1,
           const float* __restrict__ bias2, float* __restrict__ out, int Ttot){
  extern __shared__ char ldsraw[];
  unsigned short* seq_lds = (unsigned short*)ldsraw;            // [64][264]
  unsigned short* w1_lds  = seq_lds + 64 * SEQ_STRIDE;          // [64][264]
  unsigned short* w2_lds  = w1_lds + 64 * SEQ_STRIDE;           // [256][72]
  unsigned short* h_lds   = w2_lds + 256 * W2_STRIDE;           // [64][72]

  const int tid = threadIdx.x;
  const int lane = tid & 63;
  const int wv = tid >> 6;        // 0..3
  const int t0 = blockIdx.x * 64;
  const int l15 = lane & 15;
  const int lhi = lane >> 4;      // 0..3

  // stage seq tile: 64 rows x 512B
  {
    int ch = tid & 31;
    for (int r = tid >> 5; r < 64; r += 8){
      int t = t0 + r;
      int4 v = make_int4(0, 0, 0, 0);
      if (t < Ttot) v = reinterpret_cast<const int4*>(seq + (size_t)t * 256)[ch];
      *reinterpret_cast<int4*>(&seq_lds[r * SEQ_STRIDE + ch * 8]) = v;
    }
  }

  f32x4 acc2[4][4];
  #pragma unroll
  for (int a = 0; a < 4; a++)
    #pragma unroll
    for (int b = 0; b < 4; b++) acc2[a][b] = (f32x4){0.f, 0.f, 0.f, 0.f};

  for (int c = 0; c < 16; c++){
    __syncthreads();   // prev-iter LDS consumers done (also covers initial seq staging)
    {
      int ch = tid & 31;
      for (int r = tid >> 5; r < 64; r += 8){
        int4 v = reinterpret_cast<const int4*>(w1t + (size_t)(c * 64 + r) * 256)[ch];
        *reinterpret_cast<int4*>(&w1_lds[r * SEQ_STRIDE + ch * 8]) = v;
      }
      int ch2 = tid & 7;
      for (int r = tid >> 3; r < 256; r += 32){
        int4 v = *reinterpret_cast<const int4*>(w2t + (size_t)r * 1024 + c * 64 + ch2 * 8);
        *reinterpret_cast<int4*>(&w2_lds[r * W2_STRIDE + ch2 * 8]) = v;
      }
    }
    __syncthreads();

    // GEMM1: this wave computes h rows [wv*16, wv*16+16) x hidden cols [0,64), K=256
    f32x4 acc1[4];
    #pragma unroll
    for (int q = 0; q < 4; q++) acc1[q] = (f32x4){0.f, 0.f, 0.f, 0.f};
    #pragma unroll
    for (int ks = 0; ks < 8; ks++){
      short8 a = *reinterpret_cast<const short8*>(
          &seq_lds[(wv * 16 + l15) * SEQ_STRIDE + ks * 32 + lhi * 8]);
      #pragma unroll
      for (int fc = 0; fc < 4; fc++){
        short8 b = *reinterpret_cast<const short8*>(
            &w1_lds[(fc * 16 + l15) * SEQ_STRIDE + ks * 32 + lhi * 8]);
        acc1[fc] = __builtin_amdgcn_mfma_f32_16x16x32_bf16(a, b, acc1[fc], 0, 0, 0);
      }
    }
    // bias + GELU + store h tile (bf16)
    #pragma unroll
    for (int fc = 0; fc < 4; fc++){
      int hcol = fc * 16 + l15;
      float bv = bias1[c * 64 + hcol];
      #pragma unroll
      for (int q = 0; q < 4; q++){
        float v = acc1[fc][q] + bv;
        h_lds[(wv * 16 + lhi * 4 + q) * H_STRIDE + hcol] = f2bf(gelu_t(v));
      }
    }
    __syncthreads();

    // GEMM2: out rows [0,64) x cols [wv*64, wv*64+64), K=64, accumulate
    #pragma unroll
    for (int ks = 0; ks < 2; ks++){
      short8 afr[4];
      #pragma unroll
      for (int rf = 0; rf < 4; rf++)
        afr[rf] = *reinterpret_cast<const short8*>(
            &h_lds[(rf * 16 + l15) * H_STRIDE + ks * 32 + lhi * 8]);
      #pragma unroll
      for (int cf = 0; cf < 4; cf++){
        short8 b = *reinterpret_cast<const short8*>(
            &w2_lds[(wv * 64 + cf * 16 + l15) * W2_STRIDE + ks * 32 + lhi * 8]);
        #pragma unroll
        for (int rf = 0; rf < 4; rf++)
          acc2[rf][cf] = __builtin_amdgcn_mfma_f32_16x16x32_bf16(afr[rf], b, acc2[rf][cf], 0, 0, 0);
      }
    }
  }

  // epilogue: out[t][d] = acc2 + b2 (fp32)
  #pragma unroll
  for (int cf = 0; cf < 4; cf++){
    int dcol = wv * 64 + cf * 16 + l15;
    float bv = bias2[dcol];
    #pragma unroll
    for (int rf = 0; rf < 4; rf++){
      #pragma unroll
      for (int q = 0; q < 4; q++){
        int t = t0 + rf * 16 + lhi * 4 + q;
        if (t < Ttot) out[(size_t)t * 256 + dcol] = acc2[rf][cf][q] + bv;
      }
    }
  }
}

extern "C" void kernel_launch(void* const* d_in, const int* in_sizes, int n_in,
                              void* d_out, int out_size, void* d_ws, size_t ws_size,
                              hipStream_t stream){
  const float* raw = (const float*)d_in[0];
  const float* w1  = (const float*)d_in[1];
  const float* b1  = (const float*)d_in[2];
  const float* w2  = (const float*)d_in[3];
  const float* b2  = (const float*)d_in[4];
  const int* sp    = (const int*)d_in[5];
  const int* rnd   = (const int*)d_in[6];

  const int N    = in_sizes[5];          // 500000
  const int D    = in_sizes[0] / N;      // 256
  const int HID  = in_sizes[2];          // 1024
  const int SK   = in_sizes[6];          // S*K
  const int Ttot = out_size / D;         // S*(K+1) = 110000
  const int S    = Ttot - SK;            // 10000
  const int K    = SK / S;               // 10

  char* ws = (char*)d_ws;
  size_t off = 0;
  auto alloc = [&](size_t bytes) -> char* {
    char* p = ws + off;
    off += (bytes + 255) & ~(size_t)255;
    return p;
  };
  int* cnt    = (int*)alloc((size_t)S * 4);
  int* fill   = (int*)alloc((size_t)S * 4);
  int* starts = (int*)alloc((size_t)S * 4);
  int* perm   = (int*)alloc((size_t)N * 4);
  int* perm2  = (int*)alloc((size_t)N * 4);
  float* xsp  = (float*)alloc((size_t)S * D * 4);
  unsigned short* w1t = (unsigned short*)alloc((size_t)D * HID * 2);
  unsigned short* w2t = (unsigned short*)alloc((size_t)HID * D * 2);
  unsigned short* seq = (unsigned short*)alloc((size_t)Ttot * D * 2);

  hipMemsetAsync(cnt, 0, (size_t)S * 4, stream);
  hipMemsetAsync(fill, 0, (size_t)S * 4, stream);

  int nb = (N + 255) / 256;
  k_hist<<<nb, 256, 0, stream>>>(sp, cnt, N);
  k_scan<<<1, 256, 0, stream>>>(cnt, starts, S);
  k_scatter<<<nb, 256, 0, stream>>>(sp, starts, fill, perm, N);
  k_rank<<<(S + 3) / 4, 256, 0, stream>>>(perm, starts, cnt, perm2, S);
  k_pool<<<S, D, 0, stream>>>(raw, perm, starts, cnt, xsp, D);
  k_castT<<<(D * HID + 255) / 256, 256, 0, stream>>>(w1, w1t, D, HID);
  k_castT<<<(HID * D + 255) / 256, 256, 0, stream>>>(w2, w2t, HID, D);
  k_seq<<<Ttot, 64, 0, stream>>>(raw, xsp, perm2, starts, cnt, rnd, seq, S, K, N, D);

  int mlpBlocks = (Ttot + 63) / 64;
  size_t ldsBytes = (size_t)(64 * SEQ_STRIDE + 64 * SEQ_STRIDE + 256 * W2_STRIDE + 64 * H_STRIDE)
                    * sizeof(unsigned short);   // 113664 B
  hipFuncSetAttribute((const void*)k_mlp, hipFuncAttributeMaxDynamicSharedMemorySize,
                      (int)ldsBytes);
  k_mlp<<<mlpBlocks, 256, ldsBytes, stream>>>(seq, w1t, w2t, b1, b2, (float*)d_out, Ttot);
}

// Round 3
// 1054.865 us; speedup vs baseline: 1.3510x; 1.3510x over previous
//
#include <hip/hip_runtime.h>
#include <hip/hip_bf16.h>

typedef __attribute__((ext_vector_type(8))) short short8;
typedef __attribute__((ext_vector_type(4))) float f32x4;

__device__ __forceinline__ unsigned short f2bf(float f){
  __hip_bfloat16 h = __float2bfloat16(f);
  return *reinterpret_cast<unsigned short*>(&h);
}

__device__ __forceinline__ float gelu_t(float x){
  // jax.nn.gelu default (approximate=True)
  float u = 0.7978845608028654f * (x + 0.044715f * x * x * x);
  float e = __expf(2.0f * u);
  float t = 1.0f - 2.0f / (e + 1.0f);
  return 0.5f * x * (1.0f + t);
}

// ---------------- histogram ----------------
__global__ void k_hist(const int* __restrict__ sp, int* __restrict__ cnt, int N){
  int i = blockIdx.x * blockDim.x + threadIdx.x;
  if (i < N) atomicAdd(&cnt[sp[i]], 1);
}

// ---------------- exclusive scan (single block) ----------------
__global__ void k_scan(const int* __restrict__ cnt, int* __restrict__ starts, int S){
  __shared__ int part[256];
  int tid = threadIdx.x;
  int chunk = (S + 255) / 256;
  int lo = tid * chunk;
  int hi = min(lo + chunk, S);
  int sum = 0;
  for (int i = lo; i < hi; i++) sum += cnt[i];
  part[tid] = sum;
  __syncthreads();
  if (tid == 0){
    int run = 0;
    for (int i = 0; i < 256; i++){ int v = part[i]; part[i] = run; run += v; }
  }
  __syncthreads();
  int run = part[tid];
  for (int i = lo; i < hi; i++){ starts[i] = run; run += cnt[i]; }
}

// ---------------- scatter (arbitrary order within segment) ----------------
__global__ void k_scatter(const int* __restrict__ sp, const int* __restrict__ starts,
                          int* __restrict__ fill, int* __restrict__ perm, int N){
  int i = blockIdx.x * blockDim.x + threadIdx.x;
  if (i < N){
    int s = sp[i];
    int pos = atomicAdd(&fill[s], 1);
    perm[starts[s] + pos] = i;
  }
}

// ---------------- stable rank fix: one wave per superpoint ----------------
#define MAXC 512
__global__ void k_rank(const int* __restrict__ perm, const int* __restrict__ starts,
                       const int* __restrict__ cnt, int* __restrict__ perm2, int S){
  __shared__ int buf[4][MAXC];
  int wv = threadIdx.x >> 6;
  int lane = threadIdx.x & 63;
  int s = blockIdx.x * 4 + wv;
  int st = 0, c = 0;
  if (s < S){ st = starts[s]; c = cnt[s]; }
  if (c <= MAXC){
    for (int j = lane; j < c; j += 64) buf[wv][j] = perm[st + j];
  }
  __syncthreads();
  if (c <= MAXC){
    for (int j = lane; j < c; j += 64){
      int v = buf[wv][j];
      int r = 0;
      for (int m = 0; m < c; m++) r += (buf[wv][m] < v) ? 1 : 0;
      perm2[st + r] = v;   // stable order = ascending original index
    }
  } else {
    for (int j = lane; j < c; j += 64) perm2[st + j] = perm[st + j];
  }
}

// ---------------- segment mean: one block (256 thr) per superpoint, float4 ----------------
__global__ void k_pool(const float* __restrict__ raw, const int* __restrict__ perm,
                       const int* __restrict__ starts, const int* __restrict__ cnt,
                       float* __restrict__ xsp){
  __shared__ float red[4][64][4];
  int s = blockIdx.x;
  int lane = threadIdx.x & 63;
  int wv = threadIdx.x >> 6;
  int st = starts[s], c = cnt[s];
  float4 acc = make_float4(0.f, 0.f, 0.f, 0.f);
  for (int m = wv; m < c; m += 4){
    int r = perm[st + m];
    float4 v = reinterpret_cast<const float4*>(raw)[(size_t)r * 64 + lane];
    acc.x += v.x; acc.y += v.y; acc.z += v.z; acc.w += v.w;
  }
  red[wv][lane][0] = acc.x; red[wv][lane][1] = acc.y;
  red[wv][lane][2] = acc.z; red[wv][lane][3] = acc.w;
  __syncthreads();
  if (wv == 0){
    float inv = 1.0f / (float)max(c, 1);
    float4 o;
    o.x = (red[0][lane][0] + red[1][lane][0] + red[2][lane][0] + red[3][lane][0]) * inv;
    o.y = (red[0][lane][1] + red[1][lane][1] + red[2][lane][1] + red[3][lane][1]) * inv;
    o.z = (red[0][lane][2] + red[1][lane][2] + red[2][lane][2] + red[3][lane][2]) * inv;
    o.w = (red[0][lane][3] + red[1][lane][3] + red[2][lane][3] + red[3][lane][3]) * inv;
    reinterpret_cast<float4*>(xsp)[(size_t)s * 64 + lane] = o;
  }
}

// ---------------- transpose-cast fp32 [A][B] -> bf16 [B][A] ----------------
__global__ void k_castT(const float* __restrict__ in, unsigned short* __restrict__ out,
                        int A, int B){
  int i = blockIdx.x * blockDim.x + threadIdx.x;
  if (i >= A * B) return;
  int b = i / A, a = i - b * A;
  out[(size_t)b * A + a] = f2bf(in[(size_t)a * B + b]);
}

// ---------------- build seq (bf16 tokens): one block (64 thr) per token ----------------
__global__ void k_seq(const float* __restrict__ raw, const float* __restrict__ xsp,
                      const int* __restrict__ perm2, const int* __restrict__ starts,
                      const int* __restrict__ cnt, const int* __restrict__ rnd,
                      unsigned short* __restrict__ seq, int S, int K, int N, int D){
  int t = blockIdx.x;
  int lane = threadIdx.x;      // 64 threads, float4 each => 256 floats
  int kp1 = K + 1;
  int s = t / kp1;
  int j = t - s * kp1;
  const float* src;
  if (j < K){
    int c = cnt[s];
    int ml = max(c, 1);
    int gi = starts[s] + (rnd[s * K + j] % ml);
    gi = min(gi, N - 1);
    src = raw + (size_t)perm2[gi] * D;
  } else {
    src = xsp + (size_t)s * D;
  }
  float4 v = reinterpret_cast<const float4*>(src)[lane];
  ushort4 o;
  o.x = f2bf(v.x); o.y = f2bf(v.y); o.z = f2bf(v.z); o.w = f2bf(v.w);
  reinterpret_cast<ushort4*>(seq + (size_t)t * D)[lane] = o;
}

// ---------------- fused MLP v2 ----------------
// 64 tokens/block, 8 waves (512 thr). LDS (shorts, all XOR-swizzled by granule^row&7):
//   seq [64][256], w1 [64][256], h [64][64]  => 73728 B => 2 blocks/CU.
// w2 B-fragments read directly from global (L2-resident), prefetched per chunk.
__global__ __launch_bounds__(512, 4)
void k_mlp(const unsigned short* __restrict__ seq, const unsigned short* __restrict__ w1t,
           const unsigned short* __restrict__ w2t, const float* __restrict__ bias1,
           const float* __restrict__ bias2, float* __restrict__ out, int Ttot){
  extern __shared__ char ldsraw[];
  unsigned short* seq_lds = (unsigned short*)ldsraw;        // [64][256]
  unsigned short* w1_lds  = seq_lds + 64 * 256;             // [64][256]
  unsigned short* h_lds   = w1_lds + 64 * 256;              // [64][64]

  const int tid  = threadIdx.x;
  const int lane = tid & 63;
  const int wv   = tid >> 6;       // 0..7
  const int tg   = wv & 3;         // token group for GEMM1
  const int hh   = wv >> 2;        // hidden half for GEMM1
  const int l15  = lane & 15;
  const int lhi  = lane >> 4;      // 0..3
  const int t0   = blockIdx.x * 64;

  // stage seq tile (swizzled)
  #pragma unroll
  for (int rpt = 0; rpt < 4; rpt++){
    int idx = rpt * 512 + tid;           // 0..2047 granules
    int row = idx >> 5, gr = idx & 31;
    int t = t0 + row;
    int4 v = make_int4(0, 0, 0, 0);
    if (t < Ttot) v = *reinterpret_cast<const int4*>(seq + (size_t)t * 256 + gr * 8);
    *reinterpret_cast<int4*>(seq_lds + row * 256 + ((gr ^ (row & 7)) << 3)) = v;
  }

  f32x4 acc2[4][2];
  #pragma unroll
  for (int rf = 0; rf < 4; rf++)
    #pragma unroll
    for (int cf = 0; cf < 2; cf++) acc2[rf][cf] = (f32x4){0.f, 0.f, 0.f, 0.f};

  for (int c = 0; c < 16; c++){
    __syncthreads();   // prev iter's w1/h consumers done (and seq staging on c=0)

    // stage w1 chunk c (swizzled)
    #pragma unroll
    for (int rpt = 0; rpt < 4; rpt++){
      int idx = rpt * 512 + tid;
      int row = idx >> 5, gr = idx & 31;
      int4 v = *reinterpret_cast<const int4*>(w1t + (size_t)(c * 64 + row) * 256 + gr * 8);
      *reinterpret_cast<int4*>(w1_lds + row * 256 + ((gr ^ (row & 7)) << 3)) = v;
    }

    // prefetch w2 fragments + bias1 (regs; latency hides under GEMM1)
    short8 w2f[2][2];
    #pragma unroll
    for (int cf = 0; cf < 2; cf++)
      #pragma unroll
      for (int ks = 0; ks < 2; ks++)
        w2f[cf][ks] = *reinterpret_cast<const short8*>(
            w2t + (size_t)(wv * 32 + cf * 16 + l15) * 1024 + c * 64 + ks * 32 + lhi * 8);
    float bv1[2];
    bv1[0] = bias1[c * 64 + hh * 32 + l15];
    bv1[1] = bias1[c * 64 + hh * 32 + 16 + l15];

    __syncthreads();   // w1 tile ready

    // GEMM1: tokens [tg*16,+16) x hid cols [hh*32,+32), K=256
    f32x4 acc1[2];
    acc1[0] = (f32x4){0.f, 0.f, 0.f, 0.f};
    acc1[1] = (f32x4){0.f, 0.f, 0.f, 0.f};
    const int arow = tg * 16 + l15;
    #pragma unroll
    for (int ks = 0; ks < 8; ks++){
      int agr = (ks * 4 + lhi) ^ (arow & 7);
      short8 a = *reinterpret_cast<const short8*>(seq_lds + arow * 256 + agr * 8);
      #pragma unroll
      for (int fc = 0; fc < 2; fc++){
        int brow = hh * 32 + fc * 16 + l15;
        int bgr = (ks * 4 + lhi) ^ (brow & 7);
        short8 b = *reinterpret_cast<const short8*>(w1_lds + brow * 256 + bgr * 8);
        acc1[fc] = __builtin_amdgcn_mfma_f32_16x16x32_bf16(a, b, acc1[fc], 0, 0, 0);
      }
    }
    // bias + GELU -> h (swizzled b16 writes)
    #pragma unroll
    for (int fc = 0; fc < 2; fc++){
      int col = hh * 32 + fc * 16 + l15;
      #pragma unroll
      for (int q = 0; q < 4; q++){
        int row = tg * 16 + lhi * 4 + q;
        float v = acc1[fc][q] + bv1[fc];
        int phys = (col >> 3) ^ (row & 7);
        h_lds[row * 64 + phys * 8 + (col & 7)] = f2bf(gelu_t(v));
      }
    }
    __syncthreads();   // h ready

    // GEMM2: out rows [0,64) x cols [wv*32,+32), K=64 (chunk), accumulate
    #pragma unroll
    for (int ks = 0; ks < 2; ks++){
      short8 af[4];
      #pragma unroll
      for (int rf = 0; rf < 4; rf++){
        int hrow = rf * 16 + l15;
        int hgr = (ks * 4 + lhi) ^ (hrow & 7);
        af[rf] = *reinterpret_cast<const short8*>(h_lds + hrow * 64 + hgr * 8);
      }
      #pragma unroll
      for (int cf = 0; cf < 2; cf++)
        #pragma unroll
        for (int rf = 0; rf < 4; rf++)
          acc2[rf][cf] = __builtin_amdgcn_mfma_f32_16x16x32_bf16(af[rf], w2f[cf][ks],
                                                                 acc2[rf][cf], 0, 0, 0);
    }
  }

  // epilogue: out[t][d] = acc2 + b2 (fp32)
  #pragma unroll
  for (int cf = 0; cf < 2; cf++){
    int dcol = wv * 32 + cf * 16 + l15;
    float bv = bias2[dcol];
    #pragma unroll
    for (int rf = 0; rf < 4; rf++){
      #pragma unroll
      for (int q = 0; q < 4; q++){
        int t = t0 + rf * 16 + lhi * 4 + q;
        if (t < Ttot) out[(size_t)t * 256 + dcol] = acc2[rf][cf][q] + bv;
      }
    }
  }
}

extern "C" void kernel_launch(void* const* d_in, const int* in_sizes, int n_in,
                              void* d_out, int out_size, void* d_ws, size_t ws_size,
                              hipStream_t stream){
  const float* raw = (const float*)d_in[0];
  const float* w1  = (const float*)d_in[1];
  const float* b1  = (const float*)d_in[2];
  const float* w2  = (const float*)d_in[3];
  const float* b2  = (const float*)d_in[4];
  const int* sp    = (const int*)d_in[5];
  const int* rnd   = (const int*)d_in[6];

  const int N    = in_sizes[5];          // 500000
  const int D    = in_sizes[0] / N;      // 256
  const int HID  = in_sizes[2];          // 1024
  const int SK   = in_sizes[6];          // S*K
  const int Ttot = out_size / D;         // S*(K+1)
  const int S    = Ttot - SK;            // 10000
  const int K    = SK / S;               // 10

  char* ws = (char*)d_ws;
  size_t off = 0;
  auto alloc = [&](size_t bytes) -> char* {
    char* p = ws + off;
    off += (bytes + 255) & ~(size_t)255;
    return p;
  };
  int* cnt    = (int*)alloc((size_t)S * 4);
  int* fill   = (int*)alloc((size_t)S * 4);
  int* starts = (int*)alloc((size_t)S * 4);
  int* perm   = (int*)alloc((size_t)N * 4);
  int* perm2  = (int*)alloc((size_t)N * 4);
  float* xsp  = (float*)alloc((size_t)S * D * 4);
  unsigned short* w1t = (unsigned short*)alloc((size_t)D * HID * 2);
  unsigned short* w2t = (unsigned short*)alloc((size_t)HID * D * 2);
  unsigned short* seq = (unsigned short*)alloc((size_t)(S * (K + 1)) * D * 2);

  hipMemsetAsync(cnt, 0, (size_t)S * 4, stream);
  hipMemsetAsync(fill, 0, (size_t)S * 4, stream);

  int nb = (N + 255) / 256;
  k_hist<<<nb, 256, 0, stream>>>(sp, cnt, N);
  k_scan<<<1, 256, 0, stream>>>(cnt, starts, S);
  k_scatter<<<nb, 256, 0, stream>>>(sp, starts, fill, perm, N);
  k_rank<<<(S + 3) / 4, 256, 0, stream>>>(perm, starts, cnt, perm2, S);
  k_pool<<<S, 256, 0, stream>>>(raw, perm, starts, cnt, xsp);
  k_castT<<<(D * HID + 255) / 256, 256, 0, stream>>>(w1, w1t, D, HID);
  k_castT<<<(HID * D + 255) / 256, 256, 0, stream>>>(w2, w2t, HID, D);
  k_seq<<<Ttot, 64, 0, stream>>>(raw, xsp, perm2, starts, cnt, rnd, seq, S, K, N, D);

  int mlpBlocks = (Ttot + 63) / 64;
  size_t ldsBytes = (size_t)(64 * 256 + 64 * 256 + 64 * 64) * sizeof(unsigned short); // 73728
  hipFuncSetAttribute((const void*)k_mlp, hipFuncAttributeMaxDynamicSharedMemorySize,
                      (int)ldsBytes);
  k_mlp<<<mlpBlocks, 512, ldsBytes, stream>>>(seq, w1t, w2t, b1, b2, (float*)d_out, Ttot);
}